// Round 9
// baseline (607.449 us; speedup 1.0000x reference)
//
#include <hip/hip_runtime.h>

#define B_  8
#define N_  1024
#define H_  4
#define HD_ 64

// ---------------------------------------------------------------------------
// zero-fill (adjacency is atomically accumulated, must start at 0;
// harness poisons d_out with 0xAA before every launch)
// ---------------------------------------------------------------------------
__global__ void zero_f4(float4* __restrict__ p, int n4)
{
    int i  = blockIdx.x * blockDim.x + threadIdx.x;
    int st = gridDim.x * blockDim.x;
    float4 z; z.x = 0.f; z.y = 0.f; z.z = 0.f; z.w = 0.f;
    for (; i < n4; i += st) p[i] = z;
}

// ---------------------------------------------------------------------------
// Merged QKV GEMM: dst_z = A @ W_z^T + b_z, z = blockIdx.z in {0,1,2}.
// tile 128x64, 256 threads (16x16), 8x4 per thread, f32 (round-2 proven body).
// Output scattered into [b][head][n][64]. grid (64, 4, 3) = 768 blocks.
// ---------------------------------------------------------------------------
__global__ __launch_bounds__(256)
void gemm_qkv(const float* __restrict__ A,
              const float* __restrict__ W0, const float* __restrict__ b0,
              const float* __restrict__ W1, const float* __restrict__ b1,
              const float* __restrict__ W2, const float* __restrict__ b2,
              float* __restrict__ d0, float* __restrict__ d1, float* __restrict__ d2)
{
    __shared__ float At[32][132];   // transposed A tile: At[k][row]
    __shared__ float Bl[32][68];    // transposed W tile: Bl[k][col]
    const int tid = threadIdx.x;
    const int tx = tid & 15, ty = tid >> 4;
    const int brow = blockIdx.x * 128;
    const int bcol = blockIdx.y * 64;

    const float* W; const float* bias; float* dst;
    if (blockIdx.z == 0)      { W = W0; bias = b0; dst = d0; }
    else if (blockIdx.z == 1) { W = W1; bias = b1; dst = d1; }
    else                      { W = W2; bias = b2; dst = d2; }

    float acc[8][4];
    #pragma unroll
    for (int i = 0; i < 8; ++i)
        #pragma unroll
        for (int j = 0; j < 4; ++j) acc[i][j] = 0.f;

    for (int k0 = 0; k0 < 256; k0 += 32) {
        __syncthreads();
        #pragma unroll
        for (int p = 0; p < 4; ++p) {             // 128 rows x 32 k = 1024 float4
            int li = p * 256 + tid;
            int row = li >> 3, k4 = (li & 7) << 2;
            float4 v = *reinterpret_cast<const float4*>(&A[(size_t)(brow + row) * 256 + k0 + k4]);
            At[k4 + 0][row] = v.x; At[k4 + 1][row] = v.y;
            At[k4 + 2][row] = v.z; At[k4 + 3][row] = v.w;
        }
        #pragma unroll
        for (int p = 0; p < 2; ++p) {             // 64 cols x 32 k = 512 float4
            int li = p * 256 + tid;
            int c = li >> 3, k4 = (li & 7) << 2;
            float4 v = *reinterpret_cast<const float4*>(&W[(size_t)(bcol + c) * 256 + k0 + k4]);
            Bl[k4 + 0][c] = v.x; Bl[k4 + 1][c] = v.y;
            Bl[k4 + 2][c] = v.z; Bl[k4 + 3][c] = v.w;
        }
        __syncthreads();
        #pragma unroll
        for (int kk = 0; kk < 32; ++kk) {
            float4 a0 = *reinterpret_cast<const float4*>(&At[kk][ty * 8]);
            float4 a1 = *reinterpret_cast<const float4*>(&At[kk][ty * 8 + 4]);
            float4 bv = *reinterpret_cast<const float4*>(&Bl[kk][tx * 4]);
            float av[8] = {a0.x, a0.y, a0.z, a0.w, a1.x, a1.y, a1.z, a1.w};
            float bb[4] = {bv.x, bv.y, bv.z, bv.w};
            #pragma unroll
            for (int i = 0; i < 8; ++i)
                #pragma unroll
                for (int j = 0; j < 4; ++j)
                    acc[i][j] = fmaf(av[i], bb[j], acc[i][j]);
        }
    }

    float4 bvec = *reinterpret_cast<const float4*>(&bias[bcol + tx * 4]);
    float bb[4] = {bvec.x, bvec.y, bvec.z, bvec.w};
    #pragma unroll
    for (int i = 0; i < 8; ++i) {
        int row = brow + ty * 8 + i;
        float4 o;
        o.x = acc[i][0] + bb[0]; o.y = acc[i][1] + bb[1];
        o.z = acc[i][2] + bb[2]; o.w = acc[i][3] + bb[3];
        int c = bcol + tx * 4;
        int head = c >> 6, d = c & 63;
        int b = row >> 10, n = row & 1023;
        *reinterpret_cast<float4*>(&dst[(((size_t)(b * H_ + head) * N_ + n) * HD_) + d]) = o;
    }
}

// ---------------------------------------------------------------------------
// Output GEMM: C[M x 256] = A[M x 256] @ Wo^T + bo, row-major out.
// tile 128x64 (round-2 proven body). grid (64, 4).
// ---------------------------------------------------------------------------
__global__ __launch_bounds__(256)
void gemm_out(const float* __restrict__ A, const float* __restrict__ W,
              const float* __restrict__ bias, float* __restrict__ dst)
{
    __shared__ float At[32][132];
    __shared__ float Bl[32][68];
    const int tid = threadIdx.x;
    const int tx = tid & 15, ty = tid >> 4;
    const int brow = blockIdx.x * 128;
    const int bcol = blockIdx.y * 64;

    float acc[8][4];
    #pragma unroll
    for (int i = 0; i < 8; ++i)
        #pragma unroll
        for (int j = 0; j < 4; ++j) acc[i][j] = 0.f;

    for (int k0 = 0; k0 < 256; k0 += 32) {
        __syncthreads();
        #pragma unroll
        for (int p = 0; p < 4; ++p) {
            int li = p * 256 + tid;
            int row = li >> 3, k4 = (li & 7) << 2;
            float4 v = *reinterpret_cast<const float4*>(&A[(size_t)(brow + row) * 256 + k0 + k4]);
            At[k4 + 0][row] = v.x; At[k4 + 1][row] = v.y;
            At[k4 + 2][row] = v.z; At[k4 + 3][row] = v.w;
        }
        #pragma unroll
        for (int p = 0; p < 2; ++p) {
            int li = p * 256 + tid;
            int c = li >> 3, k4 = (li & 7) << 2;
            float4 v = *reinterpret_cast<const float4*>(&W[(size_t)(bcol + c) * 256 + k0 + k4]);
            Bl[k4 + 0][c] = v.x; Bl[k4 + 1][c] = v.y;
            Bl[k4 + 2][c] = v.z; Bl[k4 + 3][c] = v.w;
        }
        __syncthreads();
        #pragma unroll
        for (int kk = 0; kk < 32; ++kk) {
            float4 a0 = *reinterpret_cast<const float4*>(&At[kk][ty * 8]);
            float4 a1 = *reinterpret_cast<const float4*>(&At[kk][ty * 8 + 4]);
            float4 bv = *reinterpret_cast<const float4*>(&Bl[kk][tx * 4]);
            float av[8] = {a0.x, a0.y, a0.z, a0.w, a1.x, a1.y, a1.z, a1.w};
            float bb[4] = {bv.x, bv.y, bv.z, bv.w};
            #pragma unroll
            for (int i = 0; i < 8; ++i)
                #pragma unroll
                for (int j = 0; j < 4; ++j)
                    acc[i][j] = fmaf(av[i], bb[j], acc[i][j]);
        }
    }

    float4 bvec = *reinterpret_cast<const float4*>(&bias[bcol + tx * 4]);
    float bb[4] = {bvec.x, bvec.y, bvec.z, bvec.w};
    #pragma unroll
    for (int i = 0; i < 8; ++i) {
        int row = brow + ty * 8 + i;
        float4 o;
        o.x = acc[i][0] + bb[0]; o.y = acc[i][1] + bb[1];
        o.z = acc[i][2] + bb[2]; o.w = acc[i][3] + bb[3];
        *reinterpret_cast<float4*>(&dst[(size_t)row * 256 + bcol + tx * 4]) = o;
    }
}

// ---------------------------------------------------------------------------
// Fused scores + bias + exact top-k + softmax + adjacency(atomic) + sparse PV
// ONE (batch, head, 8-row tile) per block. block = 256 thr (4 waves).
// wave w owns rows 2w..2w+1; lane owns columns {lane + 64*j, j=0..15}.
// grid = 4096. VGPR=64 (natural) -> declare 8 waves/EU for ~full occupancy.
// ---------------------------------------------------------------------------
__global__ __launch_bounds__(256, 8)
void attn_fused(const float* __restrict__ Qg, const float* __restrict__ Kg,
                const float* __restrict__ Vg, const float* __restrict__ td,
                const int* __restrict__ topk_p,
                float* __restrict__ adj_out, float* __restrict__ Mws)
{
    __shared__ __align__(16) union {
        float kt[128 * 32];                   // kt[col][d-half], XOR-swizzled
        struct {
            float          attn[8][64];       // compacted kept attn values
            unsigned short col[8][64];        // compacted kept column indices
        } pv;                                 // alive only after score phase
    } u;
    __shared__ float Qs[8][64];               // Q tile (broadcast reads)

    const int tid  = threadIdx.x;
    const int lane = tid & 63;
    const int wv   = tid >> 6;
    const int bid  = blockIdx.x;
    const int h    = bid & 3;
    const int rt   = (bid >> 2) & 127;
    const int b    = bid >> 9;
    const int row0 = rt * 8;
    const int wrow = wv * 2;
    const size_t bh = (size_t)(b * H_ + h) * N_;

    int k = topk_p[0];
    if (k > 64) k = 64;
    if (k < 1)  k = 1;

    if (tid < 128) {   // stage Q tile: 8 rows x 64 dims (first barrier publishes)
        int r = tid >> 4, d4 = (tid & 15) << 2;
        *reinterpret_cast<float4*>(&Qs[r][d4]) =
            *reinterpret_cast<const float4*>(&Qg[(bh + row0 + r) * HD_ + d4]);
    }

    float s[2][16];
    #pragma unroll
    for (int r = 0; r < 2; ++r)
        #pragma unroll
        for (int j = 0; j < 16; ++j) s[r][j] = 0.f;

    for (int ct = 0; ct < 8; ++ct) {
        #pragma unroll
        for (int dh = 0; dh < 2; ++dh) {       // d-half: 32 dims per stage
            __syncthreads();
            #pragma unroll
            for (int p = 0; p < 4; ++p) {      // 128 cols x 8 quads = 1024 float4
                int li = p * 256 + tid;
                int col = li >> 3, d4 = (li & 7) << 2;
                float4 v = *reinterpret_cast<const float4*>(
                    &Kg[(bh + ct * 128 + col) * HD_ + dh * 32 + d4]);
                *reinterpret_cast<float4*>(
                    &u.kt[col * 32 + (d4 ^ ((col & 7) << 2))]) = v;
            }
            __syncthreads();
            #pragma unroll
            for (int d4 = 0; d4 < 32; d4 += 4) {
                float4 q0 = *reinterpret_cast<const float4*>(&Qs[wrow + 0][dh * 32 + d4]);
                float4 q1 = *reinterpret_cast<const float4*>(&Qs[wrow + 1][dh * 32 + d4]);
                #pragma unroll
                for (int jj = 0; jj < 2; ++jj) {
                    int col = jj * 64 + lane;
                    float4 kv = *reinterpret_cast<const float4*>(
                        &u.kt[col * 32 + (d4 ^ ((col & 7) << 2))]);
                    s[0][ct * 2 + jj] = fmaf(q0.x, kv.x, fmaf(q0.y, kv.y,
                                        fmaf(q0.z, kv.z, fmaf(q0.w, kv.w, s[0][ct * 2 + jj]))));
                    s[1][ct * 2 + jj] = fmaf(q1.x, kv.x, fmaf(q1.y, kv.y,
                                        fmaf(q1.z, kv.z, fmaf(q1.w, kv.w, s[1][ct * 2 + jj]))));
                }
            }
        }
    }

    __syncthreads();   // all kt reads done before pv-union writes below

    int nk[2];
    #pragma unroll
    for (int r = 0; r < 2; ++r) {
        const int row = row0 + wrow + r;
        const float* tdr = &td[((size_t)b * N_ + row) * N_];
        #pragma unroll
        for (int j = 0; j < 16; ++j) {     // scale + temporal bias
            float t = tdr[j * 64 + lane];
            s[r][j] = fmaf(s[r][j], 0.125f, -0.1f * t);
        }
        // sortable keys (monotone float->uint)
        unsigned uu[16];
        #pragma unroll
        for (int j = 0; j < 16; ++j) {
            unsigned x = __float_as_uint(s[r][j]);
            uu[j] = (x & 0x80000000u) ? ~x : (x | 0x80000000u);
        }
        // exact kth-largest key via bitwise binary search.
        // Early exit: if count(u >= tt) == k, {u>=tt} IS the exact keep-set
        // ({u>=kth} ⊆ {u>=tt}, both size k -> equal), tie-semantics preserved.
        unsigned pref = 0u;
        for (int bit = 31; bit >= 0; --bit) {
            unsigned tt = pref | (1u << bit);
            int c = 0;
            #pragma unroll
            for (int j = 0; j < 16; ++j)
                c += __popcll(__ballot(uu[j] >= tt));
            if (c >= k) {
                pref = tt;
                if (c == k) break;
            }
        }
        // row max (stable softmax)
        float m = s[r][0];
        #pragma unroll
        for (int j = 1; j < 16; ++j) m = fmaxf(m, s[r][j]);
        #pragma unroll
        for (int off = 32; off > 0; off >>= 1) m = fmaxf(m, __shfl_xor(m, off));
        // masked exp + sum (kept iff key >= threshold)
        float zs = 0.f;
        #pragma unroll
        for (int j = 0; j < 16; ++j) {
            float e = __expf(s[r][j] - m);
            e = (uu[j] >= pref) ? e : 0.f;
            s[r][j] = e;
            zs += e;
        }
        #pragma unroll
        for (int off = 32; off > 0; off >>= 1) zs += __shfl_xor(zs, off);
        const float rz = 1.f / zs;
        // adjacency atomics (kept entries only) + compact (col, attn) list
        const int slot = wrow + r;
        float* adjrow = &adj_out[((size_t)b * N_ + row) * N_];
        int cnt = 0;
        #pragma unroll
        for (int j = 0; j < 16; ++j) {
            float a = s[r][j] * rz;
            bool kp = s[r][j] > 0.f;
            unsigned long long msk = __ballot(kp);
            if (kp) {
                atomicAdd(&adjrow[j * 64 + lane], 0.25f * a);
                int pos = cnt + __popcll(msk & ((1ull << lane) - 1ull));
                if (pos < 64) {
                    u.pv.attn[slot][pos] = a;
                    u.pv.col[slot][pos]  = (unsigned short)(j * 64 + lane);
                }
            }
            cnt += __popcll(msk);
        }
        nk[r] = cnt > 64 ? 64 : cnt;
    }

    // sparse PV: lane = output dim d; ~k coalesced 256B V-row loads per row
    const float* Vb = &Vg[bh * HD_];
    #pragma unroll
    for (int r = 0; r < 2; ++r) {
        const int slot = wrow + r;
        float acc = 0.f;
        const int cnt = nk[r];
        int i = 0;
        for (; i + 4 <= cnt; i += 4) {
            float a0 = u.pv.attn[slot][i + 0]; int c0 = u.pv.col[slot][i + 0];
            float a1 = u.pv.attn[slot][i + 1]; int c1 = u.pv.col[slot][i + 1];
            float a2 = u.pv.attn[slot][i + 2]; int c2 = u.pv.col[slot][i + 2];
            float a3 = u.pv.attn[slot][i + 3]; int c3 = u.pv.col[slot][i + 3];
            acc = fmaf(a0, Vb[(size_t)c0 * HD_ + lane], acc);
            acc = fmaf(a1, Vb[(size_t)c1 * HD_ + lane], acc);
            acc = fmaf(a2, Vb[(size_t)c2 * HD_ + lane], acc);
            acc = fmaf(a3, Vb[(size_t)c3 * HD_ + lane], acc);
        }
        for (; i < cnt; ++i) {
            float a0 = u.pv.attn[slot][i]; int c0 = u.pv.col[slot][i];
            acc = fmaf(a0, Vb[(size_t)c0 * HD_ + lane], acc);
        }
        const int row = row0 + wrow + r;
        Mws[(((size_t)b * N_ + row) * H_ + h) * HD_ + lane] = acc;   // [b][n][h][d]
    }
}

// ---------------------------------------------------------------------------
extern "C" void kernel_launch(void* const* d_in, const int* in_sizes, int n_in,
                              void* d_out, int out_size, void* d_ws, size_t ws_size,
                              hipStream_t stream)
{
    const float* h  = (const float*)d_in[0];
    const float* td = (const float*)d_in[1];
    const float* Wq = (const float*)d_in[2];
    const float* bq = (const float*)d_in[3];
    const float* Wk = (const float*)d_in[4];
    const float* bk = (const float*)d_in[5];
    const float* Wv = (const float*)d_in[6];
    const float* bv = (const float*)d_in[7];
    const float* Wo = (const float*)d_in[8];
    const float* bo = (const float*)d_in[9];
    const int*   tk = (const int*)d_in[10];

    float* ws = (float*)d_ws;
    float* Q  = ws;                 // [b][h][n][64]  2,097,152 f32
    float* K  = ws + 2097152;
    float* V  = ws + 4194304;
    float* M  = ws + 6291456;       // [b][n][h][64]  2,097,152 f32

    float* adj = (float*)d_out;           // 8*1024*1024
    float* msg = (float*)d_out + 8388608; // 8*1024*256

    // zero adjacency (atomically accumulated)
    zero_f4<<<dim3(2048), dim3(256), 0, stream>>>((float4*)adj, 8 * 1024 * 1024 / 4);

    // merged QKV projection: 768 blocks (3 blocks/CU)
    gemm_qkv<<<dim3(64, 4, 3), dim3(256), 0, stream>>>(h, Wq, bq, Wk, bk, Wv, bv, Q, K, V);

    attn_fused<<<dim3(4096), dim3(256), 0, stream>>>(Q, K, V, td, tk, adj, M);

    gemm_out<<<dim3(64, 4), dim3(256), 0, stream>>>(M, Wo, bo, msg);
}

// Round 10
// 376.693 us; speedup vs baseline: 1.6126x; 1.6126x over previous
//
#include <hip/hip_runtime.h>

#define B_  8
#define N_  1024
#define H_  4
#define HD_ 64

// ---------------------------------------------------------------------------
// zero-fill (adjacency is atomically accumulated, must start at 0;
// harness poisons d_out with 0xAA before every launch)
// ---------------------------------------------------------------------------
__global__ void zero_f4(float4* __restrict__ p, int n4)
{
    int i  = blockIdx.x * blockDim.x + threadIdx.x;
    int st = gridDim.x * blockDim.x;
    float4 z; z.x = 0.f; z.y = 0.f; z.z = 0.f; z.w = 0.f;
    for (; i < n4; i += st) p[i] = z;
}

// ---------------------------------------------------------------------------
// Merged QKV GEMM: dst_z = A @ W_z^T + b_z, z = blockIdx.z in {0,1,2}.
// tile 128x64, 256 threads (16x16), 8x4 per thread, f32 (round-2 proven body).
// Output scattered into [b][head][n][64]. grid (64, 4, 3) = 768 blocks.
// ---------------------------------------------------------------------------
__global__ __launch_bounds__(256)
void gemm_qkv(const float* __restrict__ A,
              const float* __restrict__ W0, const float* __restrict__ b0,
              const float* __restrict__ W1, const float* __restrict__ b1,
              const float* __restrict__ W2, const float* __restrict__ b2,
              float* __restrict__ d0, float* __restrict__ d1, float* __restrict__ d2)
{
    __shared__ float At[32][132];   // transposed A tile: At[k][row]
    __shared__ float Bl[32][68];    // transposed W tile: Bl[k][col]
    const int tid = threadIdx.x;
    const int tx = tid & 15, ty = tid >> 4;
    const int brow = blockIdx.x * 128;
    const int bcol = blockIdx.y * 64;

    const float* W; const float* bias; float* dst;
    if (blockIdx.z == 0)      { W = W0; bias = b0; dst = d0; }
    else if (blockIdx.z == 1) { W = W1; bias = b1; dst = d1; }
    else                      { W = W2; bias = b2; dst = d2; }

    float acc[8][4];
    #pragma unroll
    for (int i = 0; i < 8; ++i)
        #pragma unroll
        for (int j = 0; j < 4; ++j) acc[i][j] = 0.f;

    for (int k0 = 0; k0 < 256; k0 += 32) {
        __syncthreads();
        #pragma unroll
        for (int p = 0; p < 4; ++p) {             // 128 rows x 32 k = 1024 float4
            int li = p * 256 + tid;
            int row = li >> 3, k4 = (li & 7) << 2;
            float4 v = *reinterpret_cast<const float4*>(&A[(size_t)(brow + row) * 256 + k0 + k4]);
            At[k4 + 0][row] = v.x; At[k4 + 1][row] = v.y;
            At[k4 + 2][row] = v.z; At[k4 + 3][row] = v.w;
        }
        #pragma unroll
        for (int p = 0; p < 2; ++p) {             // 64 cols x 32 k = 512 float4
            int li = p * 256 + tid;
            int c = li >> 3, k4 = (li & 7) << 2;
            float4 v = *reinterpret_cast<const float4*>(&W[(size_t)(bcol + c) * 256 + k0 + k4]);
            Bl[k4 + 0][c] = v.x; Bl[k4 + 1][c] = v.y;
            Bl[k4 + 2][c] = v.z; Bl[k4 + 3][c] = v.w;
        }
        __syncthreads();
        #pragma unroll
        for (int kk = 0; kk < 32; ++kk) {
            float4 a0 = *reinterpret_cast<const float4*>(&At[kk][ty * 8]);
            float4 a1 = *reinterpret_cast<const float4*>(&At[kk][ty * 8 + 4]);
            float4 bv = *reinterpret_cast<const float4*>(&Bl[kk][tx * 4]);
            float av[8] = {a0.x, a0.y, a0.z, a0.w, a1.x, a1.y, a1.z, a1.w};
            float bb[4] = {bv.x, bv.y, bv.z, bv.w};
            #pragma unroll
            for (int i = 0; i < 8; ++i)
                #pragma unroll
                for (int j = 0; j < 4; ++j)
                    acc[i][j] = fmaf(av[i], bb[j], acc[i][j]);
        }
    }

    float4 bvec = *reinterpret_cast<const float4*>(&bias[bcol + tx * 4]);
    float bb[4] = {bvec.x, bvec.y, bvec.z, bvec.w};
    #pragma unroll
    for (int i = 0; i < 8; ++i) {
        int row = brow + ty * 8 + i;
        float4 o;
        o.x = acc[i][0] + bb[0]; o.y = acc[i][1] + bb[1];
        o.z = acc[i][2] + bb[2]; o.w = acc[i][3] + bb[3];
        int c = bcol + tx * 4;
        int head = c >> 6, d = c & 63;
        int b = row >> 10, n = row & 1023;
        *reinterpret_cast<float4*>(&dst[(((size_t)(b * H_ + head) * N_ + n) * HD_) + d]) = o;
    }
}

// ---------------------------------------------------------------------------
// Output GEMM: C[M x 256] = A[M x 256] @ Wo^T + bo, row-major out.
// tile 128x64 (round-2 proven body). grid (64, 4).
// ---------------------------------------------------------------------------
__global__ __launch_bounds__(256)
void gemm_out(const float* __restrict__ A, const float* __restrict__ W,
              const float* __restrict__ bias, float* __restrict__ dst)
{
    __shared__ float At[32][132];
    __shared__ float Bl[32][68];
    const int tid = threadIdx.x;
    const int tx = tid & 15, ty = tid >> 4;
    const int brow = blockIdx.x * 128;
    const int bcol = blockIdx.y * 64;

    float acc[8][4];
    #pragma unroll
    for (int i = 0; i < 8; ++i)
        #pragma unroll
        for (int j = 0; j < 4; ++j) acc[i][j] = 0.f;

    for (int k0 = 0; k0 < 256; k0 += 32) {
        __syncthreads();
        #pragma unroll
        for (int p = 0; p < 4; ++p) {
            int li = p * 256 + tid;
            int row = li >> 3, k4 = (li & 7) << 2;
            float4 v = *reinterpret_cast<const float4*>(&A[(size_t)(brow + row) * 256 + k0 + k4]);
            At[k4 + 0][row] = v.x; At[k4 + 1][row] = v.y;
            At[k4 + 2][row] = v.z; At[k4 + 3][row] = v.w;
        }
        #pragma unroll
        for (int p = 0; p < 2; ++p) {
            int li = p * 256 + tid;
            int c = li >> 3, k4 = (li & 7) << 2;
            float4 v = *reinterpret_cast<const float4*>(&W[(size_t)(bcol + c) * 256 + k0 + k4]);
            Bl[k4 + 0][c] = v.x; Bl[k4 + 1][c] = v.y;
            Bl[k4 + 2][c] = v.z; Bl[k4 + 3][c] = v.w;
        }
        __syncthreads();
        #pragma unroll
        for (int kk = 0; kk < 32; ++kk) {
            float4 a0 = *reinterpret_cast<const float4*>(&At[kk][ty * 8]);
            float4 a1 = *reinterpret_cast<const float4*>(&At[kk][ty * 8 + 4]);
            float4 bv = *reinterpret_cast<const float4*>(&Bl[kk][tx * 4]);
            float av[8] = {a0.x, a0.y, a0.z, a0.w, a1.x, a1.y, a1.z, a1.w};
            float bb[4] = {bv.x, bv.y, bv.z, bv.w};
            #pragma unroll
            for (int i = 0; i < 8; ++i)
                #pragma unroll
                for (int j = 0; j < 4; ++j)
                    acc[i][j] = fmaf(av[i], bb[j], acc[i][j]);
        }
    }

    float4 bvec = *reinterpret_cast<const float4*>(&bias[bcol + tx * 4]);
    float bb[4] = {bvec.x, bvec.y, bvec.z, bvec.w};
    #pragma unroll
    for (int i = 0; i < 8; ++i) {
        int row = brow + ty * 8 + i;
        float4 o;
        o.x = acc[i][0] + bb[0]; o.y = acc[i][1] + bb[1];
        o.z = acc[i][2] + bb[2]; o.w = acc[i][3] + bb[3];
        *reinterpret_cast<float4*>(&dst[(size_t)row * 256 + bcol + tx * 4]) = o;
    }
}

// ---------------------------------------------------------------------------
// Fused scores + bias + exact top-k + softmax + adjacency(atomic) + sparse PV
// ONE (batch, head, 8-row tile) per block. block = 256 thr (4 waves).
// wave w owns rows 2w..2w+1; lane owns columns {lane + 64*j, j=0..15}.
// grid = 4096. launch_bounds (256,4): VGPR~64 natural, NO spill (R7/R9 lesson:
// forcing >4 waves/EU squeezes below 64 regs and spills).
// LDS: kt[32 d][130] padded, d-major: reads (d*130+col, 64 consecutive cols)
// and writes ((d4*2+col) mod 32 covers all banks) are both 2-way = FREE.
// ---------------------------------------------------------------------------
__global__ __launch_bounds__(256, 4)
void attn_fused(const float* __restrict__ Qg, const float* __restrict__ Kg,
                const float* __restrict__ Vg, const float* __restrict__ td,
                const int* __restrict__ topk_p,
                float* __restrict__ adj_out, float* __restrict__ Mws)
{
    __shared__ __align__(16) union {
        float kt[32 * 130];                   // kt[d][col], +2 pad per row
        struct {
            float          attn[8][64];       // compacted kept attn values
            unsigned short col[8][64];        // compacted kept column indices
        } pv;                                 // alive only after score phase
    } u;
    __shared__ float Qs[8][64];               // Q tile (broadcast reads)

    const int tid  = threadIdx.x;
    const int lane = tid & 63;
    const int wv   = tid >> 6;
    const int bid  = blockIdx.x;
    const int h    = bid & 3;
    const int rt   = (bid >> 2) & 127;
    const int b    = bid >> 9;
    const int row0 = rt * 8;
    const int wrow = wv * 2;
    const size_t bh = (size_t)(b * H_ + h) * N_;

    int k = topk_p[0];
    if (k > 64) k = 64;
    if (k < 1)  k = 1;

    if (tid < 128) {   // stage Q tile: 8 rows x 64 dims (first barrier publishes)
        int r = tid >> 4, d4 = (tid & 15) << 2;
        *reinterpret_cast<float4*>(&Qs[r][d4]) =
            *reinterpret_cast<const float4*>(&Qg[(bh + row0 + r) * HD_ + d4]);
    }

    float s[2][16];
    #pragma unroll
    for (int r = 0; r < 2; ++r)
        #pragma unroll
        for (int j = 0; j < 16; ++j) s[r][j] = 0.f;

    for (int ct = 0; ct < 8; ++ct) {
        #pragma unroll
        for (int dh = 0; dh < 2; ++dh) {       // d-half: 32 dims per stage
            __syncthreads();
            #pragma unroll
            for (int p = 0; p < 4; ++p) {      // 128 cols x 8 quads = 1024 float4
                int li = p * 256 + tid;
                int col = li >> 3, d4 = (li & 7) << 2;
                float4 v = *reinterpret_cast<const float4*>(
                    &Kg[(bh + ct * 128 + col) * HD_ + dh * 32 + d4]);
                u.kt[(d4 + 0) * 130 + col] = v.x;
                u.kt[(d4 + 1) * 130 + col] = v.y;
                u.kt[(d4 + 2) * 130 + col] = v.z;
                u.kt[(d4 + 3) * 130 + col] = v.w;
            }
            __syncthreads();
            #pragma unroll
            for (int d4 = 0; d4 < 32; d4 += 4) {
                float4 q0 = *reinterpret_cast<const float4*>(&Qs[wrow + 0][dh * 32 + d4]);
                float4 q1 = *reinterpret_cast<const float4*>(&Qs[wrow + 1][dh * 32 + d4]);
                #pragma unroll
                for (int jj = 0; jj < 2; ++jj) {
                    int col = jj * 64 + lane;
                    float k0v = u.kt[(d4 + 0) * 130 + col];
                    float k1v = u.kt[(d4 + 1) * 130 + col];
                    float k2v = u.kt[(d4 + 2) * 130 + col];
                    float k3v = u.kt[(d4 + 3) * 130 + col];
                    s[0][ct * 2 + jj] = fmaf(q0.x, k0v, fmaf(q0.y, k1v,
                                        fmaf(q0.z, k2v, fmaf(q0.w, k3v, s[0][ct * 2 + jj]))));
                    s[1][ct * 2 + jj] = fmaf(q1.x, k0v, fmaf(q1.y, k1v,
                                        fmaf(q1.z, k2v, fmaf(q1.w, k3v, s[1][ct * 2 + jj]))));
                }
            }
        }
    }

    __syncthreads();   // all kt reads done before pv-union writes below

    int nk[2];
    #pragma unroll
    for (int r = 0; r < 2; ++r) {
        const int row = row0 + wrow + r;
        const float* tdr = &td[((size_t)b * N_ + row) * N_];
        #pragma unroll
        for (int j = 0; j < 16; ++j) {     // scale + temporal bias
            float t = tdr[j * 64 + lane];
            s[r][j] = fmaf(s[r][j], 0.125f, -0.1f * t);
        }
        // sortable keys (monotone float->uint)
        unsigned uu[16];
        #pragma unroll
        for (int j = 0; j < 16; ++j) {
            unsigned x = __float_as_uint(s[r][j]);
            uu[j] = (x & 0x80000000u) ? ~x : (x | 0x80000000u);
        }
        // exact kth-largest key via bitwise binary search.
        // Early exit: if count(u >= tt) == k, {u>=tt} IS the exact keep-set
        // ({u>=kth} ⊆ {u>=tt}, both size k -> equal), tie-semantics preserved.
        unsigned pref = 0u;
        for (int bit = 31; bit >= 0; --bit) {
            unsigned tt = pref | (1u << bit);
            int c = 0;
            #pragma unroll
            for (int j = 0; j < 16; ++j)
                c += __popcll(__ballot(uu[j] >= tt));
            if (c >= k) {
                pref = tt;
                if (c == k) break;
            }
        }
        // row max (stable softmax)
        float m = s[r][0];
        #pragma unroll
        for (int j = 1; j < 16; ++j) m = fmaxf(m, s[r][j]);
        #pragma unroll
        for (int off = 32; off > 0; off >>= 1) m = fmaxf(m, __shfl_xor(m, off));
        // masked exp + sum (kept iff key >= threshold)
        float zs = 0.f;
        #pragma unroll
        for (int j = 0; j < 16; ++j) {
            float e = __expf(s[r][j] - m);
            e = (uu[j] >= pref) ? e : 0.f;
            s[r][j] = e;
            zs += e;
        }
        #pragma unroll
        for (int off = 32; off > 0; off >>= 1) zs += __shfl_xor(zs, off);
        const float rz = 1.f / zs;
        // adjacency atomics (kept entries only) + compact (col, attn) list
        const int slot = wrow + r;
        float* adjrow = &adj_out[((size_t)b * N_ + row) * N_];
        int cnt = 0;
        #pragma unroll
        for (int j = 0; j < 16; ++j) {
            float a = s[r][j] * rz;
            bool kp = s[r][j] > 0.f;
            unsigned long long msk = __ballot(kp);
            if (kp) {
                atomicAdd(&adjrow[j * 64 + lane], 0.25f * a);
                int pos = cnt + __popcll(msk & ((1ull << lane) - 1ull));
                if (pos < 64) {
                    u.pv.attn[slot][pos] = a;
                    u.pv.col[slot][pos]  = (unsigned short)(j * 64 + lane);
                }
            }
            cnt += __popcll(msk);
        }
        nk[r] = cnt > 64 ? 64 : cnt;
    }

    // sparse PV: lane = output dim d; ~k coalesced 256B V-row loads per row
    const float* Vb = &Vg[bh * HD_];
    #pragma unroll
    for (int r = 0; r < 2; ++r) {
        const int slot = wrow + r;
        float acc = 0.f;
        const int cnt = nk[r];
        int i = 0;
        for (; i + 4 <= cnt; i += 4) {
            float a0 = u.pv.attn[slot][i + 0]; int c0 = u.pv.col[slot][i + 0];
            float a1 = u.pv.attn[slot][i + 1]; int c1 = u.pv.col[slot][i + 1];
            float a2 = u.pv.attn[slot][i + 2]; int c2 = u.pv.col[slot][i + 2];
            float a3 = u.pv.attn[slot][i + 3]; int c3 = u.pv.col[slot][i + 3];
            acc = fmaf(a0, Vb[(size_t)c0 * HD_ + lane], acc);
            acc = fmaf(a1, Vb[(size_t)c1 * HD_ + lane], acc);
            acc = fmaf(a2, Vb[(size_t)c2 * HD_ + lane], acc);
            acc = fmaf(a3, Vb[(size_t)c3 * HD_ + lane], acc);
        }
        for (; i < cnt; ++i) {
            float a0 = u.pv.attn[slot][i]; int c0 = u.pv.col[slot][i];
            acc = fmaf(a0, Vb[(size_t)c0 * HD_ + lane], acc);
        }
        const int row = row0 + wrow + r;
        Mws[(((size_t)b * N_ + row) * H_ + h) * HD_ + lane] = acc;   // [b][n][h][d]
    }
}

// ---------------------------------------------------------------------------
extern "C" void kernel_launch(void* const* d_in, const int* in_sizes, int n_in,
                              void* d_out, int out_size, void* d_ws, size_t ws_size,
                              hipStream_t stream)
{
    const float* h  = (const float*)d_in[0];
    const float* td = (const float*)d_in[1];
    const float* Wq = (const float*)d_in[2];
    const float* bq = (const float*)d_in[3];
    const float* Wk = (const float*)d_in[4];
    const float* bk = (const float*)d_in[5];
    const float* Wv = (const float*)d_in[6];
    const float* bv = (const float*)d_in[7];
    const float* Wo = (const float*)d_in[8];
    const float* bo = (const float*)d_in[9];
    const int*   tk = (const int*)d_in[10];

    float* ws = (float*)d_ws;
    float* Q  = ws;                 // [b][h][n][64]  2,097,152 f32
    float* K  = ws + 2097152;
    float* V  = ws + 4194304;
    float* M  = ws + 6291456;       // [b][n][h][64]  2,097,152 f32

    float* adj = (float*)d_out;           // 8*1024*1024
    float* msg = (float*)d_out + 8388608; // 8*1024*256

    // zero adjacency (atomically accumulated)
    zero_f4<<<dim3(2048), dim3(256), 0, stream>>>((float4*)adj, 8 * 1024 * 1024 / 4);

    // merged QKV projection: 768 blocks (3 blocks/CU)
    gemm_qkv<<<dim3(64, 4, 3), dim3(256), 0, stream>>>(h, Wq, bq, Wk, bk, Wv, bv, Q, K, V);

    attn_fused<<<dim3(4096), dim3(256), 0, stream>>>(Q, K, V, td, tk, adj, M);

    gemm_out<<<dim3(64, 4), dim3(256), 0, stream>>>(M, Wo, bo, msg);
}